// Round 2
// baseline (709.688 us; speedup 1.0000x reference)
//
#include <hip/hip_runtime.h>
#include <math.h>

#define NN 50000
#define NE 800000
#define FF 64
#define ZD 192

typedef __attribute__((ext_vector_type(8))) short bf16x8;
typedef __attribute__((ext_vector_type(4))) float f32x4;

__device__ __forceinline__ short f2bs(float f){
  union { float f; unsigned u; } v; v.f = f;
  unsigned r = v.u + 0x7FFFu + ((v.u >> 16) & 1u);
  return (short)(r >> 16);
}
__device__ __forceinline__ float sigm(float x){ return 1.0f/(1.0f+__expf(-x)); }
__device__ __forceinline__ float sofp(float x){ return fmaxf(x,0.0f)+__logf(1.0f+__expf(-fabsf(x))); }
__device__ __forceinline__ float fsilu(float x){ return x/(1.0f+__expf(-x)); }

// ---------------------------------------------------------------------------
// k1: aout=atom copy + per-node gating-linear parts via MFMA.
//  P2[n][o]    = (Af, As)   Af[o]=sum_k atom[n][k]*wf[o][k]
//  P2[n][64+o] = (Bf, Bs)   Bf[o]=sum_k atom[n][k]*wf[o][64+k]
//  16 output-tiles: 0-3 Af, 4-7 Bf, 8-11 As, 12-15 Bs.
// ---------------------------------------------------------------------------
__global__ __launch_bounds__(256) void k1_node_pre(
    const float* __restrict__ atom,
    const float* __restrict__ wf, const float* __restrict__ ws,
    float2* __restrict__ P2, float* __restrict__ aout)
{
  int tid0 = blockIdx.x * 256 + threadIdx.x;
  int nthr = gridDim.x * 256;
  const float4* a4 = (const float4*)atom;
  float4* o4 = (float4*)aout;
  for (int i = tid0; i < NN*FF/4; i += nthr) o4[i] = a4[i];

  int lane = threadIdx.x & 63;
  int c = lane & 15, kb = lane >> 4;
  int wid = blockIdx.x * 4 + (threadIdx.x >> 6);
  int nw = gridDim.x * 4;
  for (int g = wid; g < NN/16; g += nw) {
    int n0 = g * 16;
    const float* arow = &atom[(size_t)(n0 + c) * FF + kb*8];
    bf16x8 A0, A1;
    #pragma unroll
    for (int j = 0; j < 8; j++) { A0[j] = f2bs(arow[j]); A1[j] = f2bs(arow[32+j]); }
    f32x4 acc[16];
    #pragma unroll
    for (int t = 0; t < 16; t++) acc[t] = (f32x4){0,0,0,0};
    #pragma unroll
    for (int t = 0; t < 16; t++) {
      int og = t*16 + c;
      const float* src;
      if (t < 4)       src = &wf[og*ZD];
      else if (t < 8)  src = &wf[(og-64)*ZD + 64];
      else if (t < 12) src = &ws[(og-128)*ZD];
      else             src = &ws[(og-192)*ZD + 64];
      bf16x8 B0, B1;
      #pragma unroll
      for (int j = 0; j < 8; j++) { B0[j] = f2bs(src[kb*8+j]); B1[j] = f2bs(src[32+kb*8+j]); }
      acc[t] = __builtin_amdgcn_mfma_f32_16x16x32_bf16(A0, B0, acc[t], 0,0,0);
      acc[t] = __builtin_amdgcn_mfma_f32_16x16x32_bf16(A1, B1, acc[t], 0,0,0);
    }
    // D layout: col=lane&15, row=(lane>>4)*4+reg  -> node n0+kb*4+r
    #pragma unroll
    for (int t = 0; t < 8; t++) {
      #pragma unroll
      for (int r = 0; r < 4; r++) {
        int n = n0 + kb*4 + r;
        P2[(size_t)n*128 + t*16 + c] = make_float2(acc[t][r], acc[t+8][r]);
      }
    }
  }
}

// ---------------------------------------------------------------------------
// k2: per-edge message via MFMA. 16 edges/wave.
//  9 B-tiles in regs: 0-3 zf-edge, 4-7 zs-edge, 8 fc1-edge(14 of 16).
//  D transposed through per-wave LDS -> lane=output epilogue:
//  m = sigmoid(zf)*softplus(zs)*exp(-d^2/18); atomicAdd(aout[dst]);
//  fc1-edge partial stashed in eout[e*64+0..15] (k5 consumes+overwrites).
// ---------------------------------------------------------------------------
__global__ __launch_bounds__(256) void k2_msg(
    const int* __restrict__ eidx, const float* __restrict__ efea,
    const float* __restrict__ dist,
    const float* __restrict__ wf, const float* __restrict__ ws,
    const float* __restrict__ bfb, const float* __restrict__ bsb,
    const float* __restrict__ fc1w,
    const float2* __restrict__ P2, float* __restrict__ aout,
    float* __restrict__ eout)
{
  __shared__ float stg[4][16*146];   // 37.4 KB
  int tid = threadIdx.x;
  int lane = tid & 63;
  int lw = tid >> 6;
  int c = lane & 15, kb = lane >> 4;

  bf16x8 Bf[9][2];
  #pragma unroll
  for (int t = 0; t < 9; t++) {
    int og = t*16 + c;
    const float* src = nullptr;
    if (t < 4)            src = &wf[og*ZD + 128];
    else if (t < 8)       src = &ws[(og-64)*ZD + 128];
    else if (og-128 < 14) src = &fc1w[(og-128)*ZD + 128];
    #pragma unroll
    for (int f = 0; f < 2; f++) {
      bf16x8 r;
      #pragma unroll
      for (int j = 0; j < 8; j++) r[j] = src ? f2bs(src[f*32 + kb*8 + j]) : (short)0;
      Bf[t][f] = r;
    }
  }
  float bfo = bfb[lane], bso = bsb[lane];

  int wid = blockIdx.x*4 + lw;
  int nw = gridDim.x*4;
  float* mystg = stg[lw];
  for (int g = wid; g < NE/16; g += nw) {
    int e0 = g*16;
    const float* erow = &efea[(size_t)(e0 + c)*FF + kb*8];
    bf16x8 A0, A1;
    #pragma unroll
    for (int j = 0; j < 8; j++) { A0[j] = f2bs(erow[j]); A1[j] = f2bs(erow[32+j]); }
    f32x4 acc[9];
    #pragma unroll
    for (int t = 0; t < 9; t++) acc[t] = (f32x4){0,0,0,0};
    #pragma unroll
    for (int t = 0; t < 9; t++) {
      acc[t] = __builtin_amdgcn_mfma_f32_16x16x32_bf16(A0, Bf[t][0], acc[t], 0,0,0);
      acc[t] = __builtin_amdgcn_mfma_f32_16x16x32_bf16(A1, Bf[t][1], acc[t], 0,0,0);
    }
    #pragma unroll
    for (int t = 0; t < 9; t++) {
      #pragma unroll
      for (int r = 0; r < 4; r++)
        mystg[(kb*4 + r)*146 + t*16 + c] = acc[t][r];
    }
    asm volatile("s_waitcnt lgkmcnt(0)" ::: "memory");  // in-wave LDS RAW
    #pragma unroll 2
    for (int ee = 0; ee < 16; ee++) {
      int e = e0 + ee;
      int sN = eidx[e], dN = eidx[NE + e];
      float de = dist[e];
      float wd = __expf(-de*de*(1.0f/18.0f));
      float2 vd = P2[(size_t)dN*128 + lane];        // (Af, As)
      float2 vs = P2[(size_t)sN*128 + 64 + lane];   // (Bf, Bs)
      float zf = mystg[ee*146 + lane]      + vd.x + vs.x + bfo;
      float zs = mystg[ee*146 + 64 + lane] + vd.y + vs.y + bso;
      float m = sigm(zf) * sofp(zs) * wd;
      atomicAdd(&aout[(size_t)dN*FF + lane], m);
      if (lane < 16) eout[(size_t)e*FF + lane] = mystg[ee*146 + 128 + lane];
    }
  }
}

// ---------------------------------------------------------------------------
// k3: per-node fc1 partials on UPDATED node features.
//  C[n*28+j] = sum_k aout[n][k]*fc1[j][k];  C[n*28+14+j] = ... fc1[j][64+k]
// ---------------------------------------------------------------------------
__global__ __launch_bounds__(256) void k3_cpre(
    const float* __restrict__ aout, const float* __restrict__ fc1w,
    float* __restrict__ C)
{
  __shared__ float wT[64*32];
  __shared__ float xs[4][64];
  int tid = threadIdx.x;
  for (int i = tid; i < 64*28; i += 256) {
    int k = i / 28, j = i % 28;
    wT[k*32 + j] = (j < 14) ? fc1w[j*ZD + k] : fc1w[(j-14)*ZD + 64 + k];
  }
  __syncthreads();
  int o  = tid & 63;
  int lw = tid >> 6;
  int wid = blockIdx.x * 4 + lw;
  int nw  = gridDim.x * 4;
  for (int n = wid; n < NN; n += nw) {
    xs[lw][o] = aout[(size_t)n*FF + o];
    float acc = 0.f;
    if (o < 28) {
      for (int k = 0; k < 64; k++) acc += xs[lw][k] * wT[k*32 + o];
      C[n*28 + o] = acc;
    }
  }
}

// ---------------------------------------------------------------------------
// k5: edge-update MLP. 8 edges/wave. h-edge-part read from eout stash.
// ---------------------------------------------------------------------------
__global__ __launch_bounds__(256) void k5_edge_mlp(
    const int* __restrict__ eidx,
    const float* __restrict__ fc1b,
    const float* __restrict__ fc2w, const float* __restrict__ fc2b,
    const float* __restrict__ C, float* __restrict__ eout)
{
  __shared__ float w2T[14*64];
  __shared__ float hs[4][128];
  int tid = threadIdx.x;
  for (int i = tid; i < 14*64; i += 256) {
    int j = i >> 6, o = i & 63;
    w2T[i] = fc2w[o*14 + j];
  }
  __syncthreads();
  int o  = tid & 63;
  int lw = tid >> 6;
  int j4 = o >> 2, q = o & 3;
  int wid = blockIdx.x*4 + lw;
  int nw  = gridDim.x*4;
  for (int g = wid; g < NE/8; g += nw) {
    int e0 = g*8;
    #pragma unroll
    for (int pass = 0; pass < 2; pass++) {
      int ee = pass*4 + q;
      int e = e0 + ee;
      if (j4 < 14) {
        int sN = eidx[e], dN = eidx[NE+e];
        float h = eout[(size_t)e*FF + j4] + C[sN*28 + j4] + C[dN*28 + 14 + j4] + fc1b[j4];
        hs[lw][ee*16 + j4] = fsilu(h);
      }
    }
    asm volatile("s_waitcnt lgkmcnt(0)" ::: "memory");  // in-wave LDS RAW
    float b2 = fc2b[o];
    #pragma unroll
    for (int ee = 0; ee < 8; ee++) {
      float acc = b2;
      #pragma unroll
      for (int jj = 0; jj < 14; jj++)
        acc += w2T[jj*64 + o] * hs[lw][ee*16 + jj];
      eout[(size_t)(e0 + ee)*FF + o] = fsilu(acc);
    }
  }
}

// ---------------------------------------------------------------------------
extern "C" void kernel_launch(void* const* d_in, const int* in_sizes, int n_in,
                              void* d_out, int out_size, void* d_ws, size_t ws_size,
                              hipStream_t stream) {
  const float* atom  = (const float*)d_in[0];
  const int*   eidx  = (const int*)  d_in[1];
  const float* efea  = (const float*)d_in[2];
  const float* dist  = (const float*)d_in[4];
  const float* wf    = (const float*)d_in[6];
  const float* bf    = (const float*)d_in[7];
  const float* ws    = (const float*)d_in[8];
  const float* bs    = (const float*)d_in[9];
  const float* fc1w  = (const float*)d_in[10];
  const float* fc1b  = (const float*)d_in[11];
  const float* fc2w  = (const float*)d_in[12];
  const float* fc2b  = (const float*)d_in[13];

  float* aout = (float*)d_out;                 // [50000, 64]
  float* eout = aout + (size_t)NN * FF;        // [800000, 64]

  float2* P2 = (float2*)d_ws;                                  // 51.2 MB
  float*  C  = (float*)((char*)d_ws + (size_t)NN * 128 * 8);   // +5.6 MB

  hipLaunchKernelGGL(k1_node_pre, dim3(512), dim3(256), 0, stream,
                     atom, wf, ws, P2, aout);
  hipLaunchKernelGGL(k2_msg, dim3(2048), dim3(256), 0, stream,
                     eidx, efea, dist, wf, ws, bf, bs, fc1w, P2, aout, eout);
  hipLaunchKernelGGL(k3_cpre, dim3(512), dim3(256), 0, stream,
                     aout, fc1w, C);
  hipLaunchKernelGGL(k5_edge_mlp, dim3(2048), dim3(256), 0, stream,
                     eidx, fc1b, fc2w, fc2b, C, eout);
}

// Round 4
// 432.232 us; speedup vs baseline: 1.6419x; 1.6419x over previous
//
#include <hip/hip_runtime.h>
#include <math.h>

#define NN 50000
#define NE 800000
#define FF 64
#define ZD 192

typedef __attribute__((ext_vector_type(8))) short bf16x8;
typedef __attribute__((ext_vector_type(4))) float f32x4;

__device__ __forceinline__ short f2bs(float f){
  union { float f; unsigned u; } v; v.f = f;
  unsigned r = v.u + 0x7FFFu + ((v.u >> 16) & 1u);
  return (short)(r >> 16);
}
__device__ __forceinline__ float sigm(float x){ return 1.0f/(1.0f+__expf(-x)); }
__device__ __forceinline__ float sofp(float x){ return fmaxf(x,0.0f)+__logf(1.0f+__expf(-fabsf(x))); }
__device__ __forceinline__ float fsilu(float x){ return x/(1.0f+__expf(-x)); }

// ---------------------------------------------------------------------------
// k1: aout=atom copy + per-node gating-linear parts via MFMA.
//  P2[n][o]    = (Af, As) ; P2[n][64+o] = (Bf, Bs)
// ---------------------------------------------------------------------------
__global__ __launch_bounds__(256) void k1_node_pre(
    const float* __restrict__ atom,
    const float* __restrict__ wf, const float* __restrict__ ws,
    float2* __restrict__ P2, float* __restrict__ aout)
{
  int tid0 = blockIdx.x * 256 + threadIdx.x;
  int nthr = gridDim.x * 256;
  const float4* a4 = (const float4*)atom;
  float4* o4 = (float4*)aout;
  for (int i = tid0; i < NN*FF/4; i += nthr) o4[i] = a4[i];

  int lane = threadIdx.x & 63;
  int c = lane & 15, kb = lane >> 4;
  int wid = blockIdx.x * 4 + (threadIdx.x >> 6);
  int nw = gridDim.x * 4;
  for (int g = wid; g < NN/16; g += nw) {
    int n0 = g * 16;
    const float* arow = &atom[(size_t)(n0 + c) * FF + kb*8];
    bf16x8 A0, A1;
    #pragma unroll
    for (int j = 0; j < 8; j++) { A0[j] = f2bs(arow[j]); A1[j] = f2bs(arow[32+j]); }
    f32x4 acc[16];
    #pragma unroll
    for (int t = 0; t < 16; t++) acc[t] = (f32x4){0,0,0,0};
    #pragma unroll
    for (int t = 0; t < 16; t++) {
      int og = t*16 + c;
      const float* src;
      if (t < 4)       src = &wf[og*ZD];
      else if (t < 8)  src = &wf[(og-64)*ZD + 64];
      else if (t < 12) src = &ws[(og-128)*ZD];
      else             src = &ws[(og-192)*ZD + 64];
      bf16x8 B0, B1;
      #pragma unroll
      for (int j = 0; j < 8; j++) { B0[j] = f2bs(src[kb*8+j]); B1[j] = f2bs(src[32+kb*8+j]); }
      acc[t] = __builtin_amdgcn_mfma_f32_16x16x32_bf16(A0, B0, acc[t], 0,0,0);
      acc[t] = __builtin_amdgcn_mfma_f32_16x16x32_bf16(A1, B1, acc[t], 0,0,0);
    }
    #pragma unroll
    for (int t = 0; t < 8; t++) {
      #pragma unroll
      for (int r = 0; r < 4; r++) {
        int n = n0 + kb*4 + r;
        P2[(size_t)n*128 + t*16 + c] = make_float2(acc[t][r], acc[t+8][r]);
      }
    }
  }
}

// ---------------------------------------------------------------------------
// k2: per-edge message via MFMA, latency-optimized epilogue.
//  - eidx/dist loaded vectorized once per 16-edge group, shfl-broadcast
//  - P2 gathers batched 8 edges deep (16 loads in flight)
//  - fc1-edge stash straight from fragment.  D layout: row(=edge)=kb*4+r,
//    col(=output j)=c  [the R3 bug was swapping these]
// ---------------------------------------------------------------------------
__global__ __launch_bounds__(256) void k2_msg(
    const int* __restrict__ eidx, const float* __restrict__ efea,
    const float* __restrict__ dist,
    const float* __restrict__ wf, const float* __restrict__ ws,
    const float* __restrict__ bfb, const float* __restrict__ bsb,
    const float* __restrict__ fc1w,
    const float2* __restrict__ P2, float* __restrict__ aout,
    float* __restrict__ eout)
{
  __shared__ float stg[4][16*130];   // 33.3 KB: zf|zs transposed, 16 edges x 128 (+2 pad)
  int tid = threadIdx.x;
  int lane = tid & 63;
  int lw = tid >> 6;
  int c = lane & 15, kb = lane >> 4;

  bf16x8 Bf[9][2];
  #pragma unroll
  for (int t = 0; t < 9; t++) {
    int og = t*16 + c;
    const float* src = nullptr;
    if (t < 4)            src = &wf[og*ZD + 128];
    else if (t < 8)       src = &ws[(og-64)*ZD + 128];
    else if (og-128 < 14) src = &fc1w[(og-128)*ZD + 128];
    #pragma unroll
    for (int f = 0; f < 2; f++) {
      bf16x8 r;
      #pragma unroll
      for (int j = 0; j < 8; j++) r[j] = src ? f2bs(src[f*32 + kb*8 + j]) : (short)0;
      Bf[t][f] = r;
    }
  }
  float bfo = bfb[lane], bso = bsb[lane];

  int wid = blockIdx.x*4 + lw;
  int nw = gridDim.x*4;
  float* mystg = stg[lw];
  for (int g = wid; g < NE/16; g += nw) {
    int e0 = g*16;
    // vectorized per-group scalars (16 valid lanes, replicated 4x)
    int  sNv = eidx[e0 + (lane & 15)];
    int  dNv = eidx[NE + e0 + (lane & 15)];
    float dev = dist[e0 + (lane & 15)];
    float wdv = __expf(-dev*dev*(1.0f/18.0f));

    const float* erow = &efea[(size_t)(e0 + c)*FF + kb*8];
    bf16x8 A0, A1;
    #pragma unroll
    for (int j = 0; j < 8; j++) { A0[j] = f2bs(erow[j]); A1[j] = f2bs(erow[32+j]); }
    f32x4 acc[9];
    #pragma unroll
    for (int t = 0; t < 9; t++) acc[t] = (f32x4){0,0,0,0};
    #pragma unroll
    for (int t = 0; t < 9; t++) {
      acc[t] = __builtin_amdgcn_mfma_f32_16x16x32_bf16(A0, Bf[t][0], acc[t], 0,0,0);
      acc[t] = __builtin_amdgcn_mfma_f32_16x16x32_bf16(A1, Bf[t][1], acc[t], 0,0,0);
    }
    // fc1-edge stash: D row = edge = kb*4+r, D col = j = c (c<14 valid)
    if (c < 14) {
      #pragma unroll
      for (int r = 0; r < 4; r++)
        eout[(size_t)(e0 + kb*4 + r)*FF + c] = acc[8][r];
    }
    // transpose zf/zs through LDS
    #pragma unroll
    for (int t = 0; t < 8; t++) {
      #pragma unroll
      for (int r = 0; r < 4; r++)
        mystg[(kb*4 + r)*130 + t*16 + c] = acc[t][r];
    }
    asm volatile("s_waitcnt lgkmcnt(0)" ::: "memory");  // in-wave LDS RAW
    #pragma unroll
    for (int half = 0; half < 2; half++) {
      int   sN[8], dN[8];
      float wd8[8];
      float2 vd[8], vs[8];
      #pragma unroll
      for (int u = 0; u < 8; u++) {
        int ee = half*8 + u;
        sN[u]  = __shfl(sNv, ee, 64);
        dN[u]  = __shfl(dNv, ee, 64);
        wd8[u] = __shfl(wdv, ee, 64);
      }
      #pragma unroll
      for (int u = 0; u < 8; u++) {       // 16 independent gathers in flight
        vd[u] = P2[(size_t)dN[u]*128 + lane];
        vs[u] = P2[(size_t)sN[u]*128 + 64 + lane];
      }
      #pragma unroll
      for (int u = 0; u < 8; u++) {
        int ee = half*8 + u;
        float zf = mystg[ee*130 + lane]      + vd[u].x + vs[u].x + bfo;
        float zs = mystg[ee*130 + 64 + lane] + vd[u].y + vs[u].y + bso;
        float m = sigm(zf) * sofp(zs) * wd8[u];
        atomicAdd(&aout[(size_t)dN[u]*FF + lane], m);
      }
    }
  }
}

// ---------------------------------------------------------------------------
// k3: per-node fc1 partials on UPDATED node features.
// ---------------------------------------------------------------------------
__global__ __launch_bounds__(256) void k3_cpre(
    const float* __restrict__ aout, const float* __restrict__ fc1w,
    float* __restrict__ C)
{
  __shared__ float wT[64*32];
  __shared__ float xs[4][64];
  int tid = threadIdx.x;
  for (int i = tid; i < 64*28; i += 256) {
    int k = i / 28, j = i % 28;
    wT[k*32 + j] = (j < 14) ? fc1w[j*ZD + k] : fc1w[(j-14)*ZD + 64 + k];
  }
  __syncthreads();
  int o  = tid & 63;
  int lw = tid >> 6;
  int wid = blockIdx.x * 4 + lw;
  int nw  = gridDim.x * 4;
  for (int n = wid; n < NN; n += nw) {
    xs[lw][o] = aout[(size_t)n*FF + o];
    float acc = 0.f;
    if (o < 28) {
      for (int k = 0; k < 64; k++) acc += xs[lw][k] * wT[k*32 + o];
      C[n*28 + o] = acc;
    }
  }
}

// ---------------------------------------------------------------------------
// k5: edge-update MLP. 8 edges/wave. h-edge-part read from eout stash.
// ---------------------------------------------------------------------------
__global__ __launch_bounds__(256) void k5_edge_mlp(
    const int* __restrict__ eidx,
    const float* __restrict__ fc1b,
    const float* __restrict__ fc2w, const float* __restrict__ fc2b,
    const float* __restrict__ C, float* __restrict__ eout)
{
  __shared__ float w2T[14*64];
  __shared__ float hs[4][128];
  int tid = threadIdx.x;
  for (int i = tid; i < 14*64; i += 256) {
    int j = i >> 6, o = i & 63;
    w2T[i] = fc2w[o*14 + j];
  }
  __syncthreads();
  int o  = tid & 63;
  int lw = tid >> 6;
  int j4 = o >> 2, q = o & 3;
  int wid = blockIdx.x*4 + lw;
  int nw  = gridDim.x*4;
  for (int g = wid; g < NE/8; g += nw) {
    int e0 = g*8;
    #pragma unroll
    for (int pass = 0; pass < 2; pass++) {
      int ee = pass*4 + q;
      int e = e0 + ee;
      if (j4 < 14) {
        int sN = eidx[e], dN = eidx[NE+e];
        float h = eout[(size_t)e*FF + j4] + C[sN*28 + j4] + C[dN*28 + 14 + j4] + fc1b[j4];
        hs[lw][ee*16 + j4] = fsilu(h);
      }
    }
    asm volatile("s_waitcnt lgkmcnt(0)" ::: "memory");  // in-wave LDS RAW
    float b2 = fc2b[o];
    #pragma unroll
    for (int ee = 0; ee < 8; ee++) {
      float acc = b2;
      #pragma unroll
      for (int jj = 0; jj < 14; jj++)
        acc += w2T[jj*64 + o] * hs[lw][ee*16 + jj];
      eout[(size_t)(e0 + ee)*FF + o] = fsilu(acc);
    }
  }
}

// ---------------------------------------------------------------------------
extern "C" void kernel_launch(void* const* d_in, const int* in_sizes, int n_in,
                              void* d_out, int out_size, void* d_ws, size_t ws_size,
                              hipStream_t stream) {
  const float* atom  = (const float*)d_in[0];
  const int*   eidx  = (const int*)  d_in[1];
  const float* efea  = (const float*)d_in[2];
  const float* dist  = (const float*)d_in[4];
  const float* wf    = (const float*)d_in[6];
  const float* bf    = (const float*)d_in[7];
  const float* ws    = (const float*)d_in[8];
  const float* bs    = (const float*)d_in[9];
  const float* fc1w  = (const float*)d_in[10];
  const float* fc1b  = (const float*)d_in[11];
  const float* fc2w  = (const float*)d_in[12];
  const float* fc2b  = (const float*)d_in[13];

  float* aout = (float*)d_out;                 // [50000, 64]
  float* eout = aout + (size_t)NN * FF;        // [800000, 64]

  float2* P2 = (float2*)d_ws;                                  // 51.2 MB
  float*  C  = (float*)((char*)d_ws + (size_t)NN * 128 * 8);   // +5.6 MB

  hipLaunchKernelGGL(k1_node_pre, dim3(512), dim3(256), 0, stream,
                     atom, wf, ws, P2, aout);
  hipLaunchKernelGGL(k2_msg, dim3(1024), dim3(256), 0, stream,
                     eidx, efea, dist, wf, ws, bf, bs, fc1w, P2, aout, eout);
  hipLaunchKernelGGL(k3_cpre, dim3(512), dim3(256), 0, stream,
                     aout, fc1w, C);
  hipLaunchKernelGGL(k5_edge_mlp, dim3(2048), dim3(256), 0, stream,
                     eidx, fc1b, fc2w, fc2b, C, eout);
}

// Round 5
// 413.280 us; speedup vs baseline: 1.7172x; 1.0459x over previous
//
#include <hip/hip_runtime.h>
#include <math.h>

#define NN 50000
#define NE 800000
#define FF 64
#define ZD 192

typedef __attribute__((ext_vector_type(8))) short bf16x8;
typedef __attribute__((ext_vector_type(4))) float f32x4;

__device__ __forceinline__ short f2bs(float f){
  union { float f; unsigned u; } v; v.f = f;
  unsigned r = v.u + 0x7FFFu + ((v.u >> 16) & 1u);
  return (short)(r >> 16);
}
__device__ __forceinline__ unsigned packbf(float a, float b){
  return ((unsigned)(unsigned short)f2bs(b) << 16) | (unsigned)(unsigned short)f2bs(a);
}
__device__ __forceinline__ float lo16f(unsigned u){ union{unsigned u; float f;} v; v.u = u << 16; return v.f; }
__device__ __forceinline__ float hi16f(unsigned u){ union{unsigned u; float f;} v; v.u = u & 0xFFFF0000u; return v.f; }
__device__ __forceinline__ float sigm(float x){ return 1.0f/(1.0f+__expf(-x)); }
__device__ __forceinline__ float sofp(float x){ return fmaxf(x,0.0f)+__logf(1.0f+__expf(-fabsf(x))); }
__device__ __forceinline__ float fsilu(float x){ return x/(1.0f+__expf(-x)); }

// ---------------------------------------------------------------------------
// k1: aout=atom copy + per-node gating-linear parts via MFMA.
//  P2u[n*128 + o]      = packbf(Af[o], As[o])
//  P2u[n*128 + 64 + o] = packbf(Bf[o], Bs[o])
// ---------------------------------------------------------------------------
__global__ __launch_bounds__(256) void k1_node_pre(
    const float* __restrict__ atom,
    const float* __restrict__ wf, const float* __restrict__ ws,
    unsigned* __restrict__ P2u, float* __restrict__ aout)
{
  int tid0 = blockIdx.x * 256 + threadIdx.x;
  int nthr = gridDim.x * 256;
  const float4* a4 = (const float4*)atom;
  float4* o4 = (float4*)aout;
  for (int i = tid0; i < NN*FF/4; i += nthr) o4[i] = a4[i];

  int lane = threadIdx.x & 63;
  int c = lane & 15, kb = lane >> 4;
  int wid = blockIdx.x * 4 + (threadIdx.x >> 6);
  int nw = gridDim.x * 4;
  for (int g = wid; g < NN/16; g += nw) {
    int n0 = g * 16;
    const float* arow = &atom[(size_t)(n0 + c) * FF + kb*8];
    bf16x8 A0, A1;
    #pragma unroll
    for (int j = 0; j < 8; j++) { A0[j] = f2bs(arow[j]); A1[j] = f2bs(arow[32+j]); }
    f32x4 acc[16];
    #pragma unroll
    for (int t = 0; t < 16; t++) acc[t] = (f32x4){0,0,0,0};
    #pragma unroll
    for (int t = 0; t < 16; t++) {
      int og = t*16 + c;
      const float* src;
      if (t < 4)       src = &wf[og*ZD];
      else if (t < 8)  src = &wf[(og-64)*ZD + 64];
      else if (t < 12) src = &ws[(og-128)*ZD];
      else             src = &ws[(og-192)*ZD + 64];
      bf16x8 B0, B1;
      #pragma unroll
      for (int j = 0; j < 8; j++) { B0[j] = f2bs(src[kb*8+j]); B1[j] = f2bs(src[32+kb*8+j]); }
      acc[t] = __builtin_amdgcn_mfma_f32_16x16x32_bf16(A0, B0, acc[t], 0,0,0);
      acc[t] = __builtin_amdgcn_mfma_f32_16x16x32_bf16(A1, B1, acc[t], 0,0,0);
    }
    // D: col=c (output within tile), row=kb*4+r (node)
    #pragma unroll
    for (int t = 0; t < 8; t++) {
      #pragma unroll
      for (int r = 0; r < 4; r++) {
        int n = n0 + kb*4 + r;
        P2u[(size_t)n*128 + t*16 + c] = packbf(acc[t][r], acc[t+8][r]);
      }
    }
  }
}

// ---------------------------------------------------------------------------
// k2: per-edge message via MFMA. 16 edges/wave, zero LDS.
//  Epilogue runs in fragment layout: lane (c,kb) holds outputs o=t*16+c for
//  edges kb*4+r.  Per-edge dN/sN/wd shfl-broadcast; P2 gathered as packed
//  bf16 dwords; atomicAdd per (t,r) -> 4 nodes x 64B segments.
// ---------------------------------------------------------------------------
__global__ __launch_bounds__(256) void k2_msg(
    const int* __restrict__ eidx, const float* __restrict__ efea,
    const float* __restrict__ dist,
    const float* __restrict__ wf, const float* __restrict__ ws,
    const float* __restrict__ bfb, const float* __restrict__ bsb,
    const float* __restrict__ fc1w,
    const unsigned* __restrict__ P2u, float* __restrict__ aout,
    float* __restrict__ eout)
{
  int tid = threadIdx.x;
  int lane = tid & 63;
  int lw = tid >> 6;
  int c = lane & 15, kb = lane >> 4;

  bf16x8 Bf[9][2];
  #pragma unroll
  for (int t = 0; t < 9; t++) {
    int og = t*16 + c;
    const float* src = nullptr;
    if (t < 4)            src = &wf[og*ZD + 128];
    else if (t < 8)       src = &ws[(og-64)*ZD + 128];
    else if (og-128 < 14) src = &fc1w[(og-128)*ZD + 128];
    #pragma unroll
    for (int f = 0; f < 2; f++) {
      bf16x8 r;
      #pragma unroll
      for (int j = 0; j < 8; j++) r[j] = src ? f2bs(src[f*32 + kb*8 + j]) : (short)0;
      Bf[t][f] = r;
    }
  }
  float bfo[4], bso[4];
  #pragma unroll
  for (int t = 0; t < 4; t++) { bfo[t] = bfb[t*16+c]; bso[t] = bsb[t*16+c]; }

  int wid = blockIdx.x*4 + lw;
  int nw = gridDim.x*4;
  for (int g = wid; g < NE/16; g += nw) {
    int e0 = g*16;
    // vectorized per-group scalars (16 valid lanes, replicated 4x)
    int   sNv = eidx[e0 + (lane & 15)];
    int   dNv = eidx[NE + e0 + (lane & 15)];
    float dev = dist[e0 + (lane & 15)];
    float wdv = __expf(-dev*dev*(1.0f/18.0f));

    const float* erow = &efea[(size_t)(e0 + c)*FF + kb*8];
    bf16x8 A0, A1;
    #pragma unroll
    for (int j = 0; j < 8; j++) { A0[j] = f2bs(erow[j]); A1[j] = f2bs(erow[32+j]); }
    f32x4 acc[9];
    #pragma unroll
    for (int t = 0; t < 9; t++) acc[t] = (f32x4){0,0,0,0};
    #pragma unroll
    for (int t = 0; t < 9; t++) {
      acc[t] = __builtin_amdgcn_mfma_f32_16x16x32_bf16(A0, Bf[t][0], acc[t], 0,0,0);
      acc[t] = __builtin_amdgcn_mfma_f32_16x16x32_bf16(A1, Bf[t][1], acc[t], 0,0,0);
    }
    // fc1-edge stash: D row = edge = kb*4+r, D col = j = c (c<14 valid)
    if (c < 14) {
      #pragma unroll
      for (int r = 0; r < 4; r++)
        eout[(size_t)(e0 + kb*4 + r)*FF + c] = acc[8][r];
    }
    // epilogue in fragment layout
    int sN[4], dN[4]; float wd[4];
    #pragma unroll
    for (int r = 0; r < 4; r++) {
      sN[r] = __shfl(sNv, kb*4 + r, 64);
      dN[r] = __shfl(dNv, kb*4 + r, 64);
      wd[r] = __shfl(wdv, kb*4 + r, 64);
    }
    unsigned vdu[4][4], vsu[4][4];
    #pragma unroll
    for (int r = 0; r < 4; r++) {
      #pragma unroll
      for (int t = 0; t < 4; t++) {
        vdu[r][t] = P2u[(size_t)dN[r]*128 + t*16 + c];
        vsu[r][t] = P2u[(size_t)sN[r]*128 + 64 + t*16 + c];
      }
    }
    #pragma unroll
    for (int r = 0; r < 4; r++) {
      #pragma unroll
      for (int t = 0; t < 4; t++) {
        float zf = acc[t][r]   + lo16f(vdu[r][t]) + lo16f(vsu[r][t]) + bfo[t];
        float zs = acc[t+4][r] + hi16f(vdu[r][t]) + hi16f(vsu[r][t]) + bso[t];
        float m = sigm(zf) * sofp(zs) * wd[r];
        atomicAdd(&aout[(size_t)dN[r]*FF + t*16 + c], m);
      }
    }
  }
}

// ---------------------------------------------------------------------------
// k3: per-node fc1 partials on UPDATED node features.
// ---------------------------------------------------------------------------
__global__ __launch_bounds__(256) void k3_cpre(
    const float* __restrict__ aout, const float* __restrict__ fc1w,
    float* __restrict__ C)
{
  __shared__ float wT[64*32];
  __shared__ float xs[4][64];
  int tid = threadIdx.x;
  for (int i = tid; i < 64*28; i += 256) {
    int k = i / 28, j = i % 28;
    wT[k*32 + j] = (j < 14) ? fc1w[j*ZD + k] : fc1w[(j-14)*ZD + 64 + k];
  }
  __syncthreads();
  int o  = tid & 63;
  int lw = tid >> 6;
  int wid = blockIdx.x * 4 + lw;
  int nw  = gridDim.x * 4;
  for (int n = wid; n < NN; n += nw) {
    xs[lw][o] = aout[(size_t)n*FF + o];
    float acc = 0.f;
    if (o < 28) {
      for (int k = 0; k < 64; k++) acc += xs[lw][k] * wT[k*32 + o];
      C[n*28 + o] = acc;
    }
  }
}

// ---------------------------------------------------------------------------
// k5: edge-update MLP. 8 edges/wave. h-edge-part read from eout stash.
// ---------------------------------------------------------------------------
__global__ __launch_bounds__(256) void k5_edge_mlp(
    const int* __restrict__ eidx,
    const float* __restrict__ fc1b,
    const float* __restrict__ fc2w, const float* __restrict__ fc2b,
    const float* __restrict__ C, float* __restrict__ eout)
{
  __shared__ float w2T[14*64];
  __shared__ float hs[4][128];
  int tid = threadIdx.x;
  for (int i = tid; i < 14*64; i += 256) {
    int j = i >> 6, o = i & 63;
    w2T[i] = fc2w[o*14 + j];
  }
  __syncthreads();
  int o  = tid & 63;
  int lw = tid >> 6;
  int j4 = o >> 2, q = o & 3;
  int wid = blockIdx.x*4 + lw;
  int nw  = gridDim.x*4;
  for (int g = wid; g < NE/8; g += nw) {
    int e0 = g*8;
    #pragma unroll
    for (int pass = 0; pass < 2; pass++) {
      int ee = pass*4 + q;
      int e = e0 + ee;
      if (j4 < 14) {
        int sN = eidx[e], dN = eidx[NE+e];
        float h = eout[(size_t)e*FF + j4] + C[sN*28 + j4] + C[dN*28 + 14 + j4] + fc1b[j4];
        hs[lw][ee*16 + j4] = fsilu(h);
      }
    }
    asm volatile("s_waitcnt lgkmcnt(0)" ::: "memory");  // in-wave LDS RAW
    float b2 = fc2b[o];
    #pragma unroll
    for (int ee = 0; ee < 8; ee++) {
      float acc = b2;
      #pragma unroll
      for (int jj = 0; jj < 14; jj++)
        acc += w2T[jj*64 + o] * hs[lw][ee*16 + jj];
      eout[(size_t)(e0 + ee)*FF + o] = fsilu(acc);
    }
  }
}

// ---------------------------------------------------------------------------
extern "C" void kernel_launch(void* const* d_in, const int* in_sizes, int n_in,
                              void* d_out, int out_size, void* d_ws, size_t ws_size,
                              hipStream_t stream) {
  const float* atom  = (const float*)d_in[0];
  const int*   eidx  = (const int*)  d_in[1];
  const float* efea  = (const float*)d_in[2];
  const float* dist  = (const float*)d_in[4];
  const float* wf    = (const float*)d_in[6];
  const float* bf    = (const float*)d_in[7];
  const float* ws    = (const float*)d_in[8];
  const float* bs    = (const float*)d_in[9];
  const float* fc1w  = (const float*)d_in[10];
  const float* fc1b  = (const float*)d_in[11];
  const float* fc2w  = (const float*)d_in[12];
  const float* fc2b  = (const float*)d_in[13];

  float* aout = (float*)d_out;                 // [50000, 64]
  float* eout = aout + (size_t)NN * FF;        // [800000, 64]

  unsigned* P2u = (unsigned*)d_ws;                             // 25.6 MB
  float*    C   = (float*)((char*)d_ws + (size_t)NN * 128 * 4); // +5.6 MB

  hipLaunchKernelGGL(k1_node_pre, dim3(512), dim3(256), 0, stream,
                     atom, wf, ws, P2u, aout);
  hipLaunchKernelGGL(k2_msg, dim3(1024), dim3(256), 0, stream,
                     eidx, efea, dist, wf, ws, bf, bs, fc1w, P2u, aout, eout);
  hipLaunchKernelGGL(k3_cpre, dim3(512), dim3(256), 0, stream,
                     aout, fc1w, C);
  hipLaunchKernelGGL(k5_edge_mlp, dim3(2048), dim3(256), 0, stream,
                     eidx, fc1b, fc2w, fc2b, C, eout);
}